// Round 12
// baseline (483.485 us; speedup 1.0000x reference)
//
#include <hip/hip_runtime.h>
#include <hip/hip_bf16.h>

#define LN2F 0.69314718055994530942f

typedef short bf16x8 __attribute__((ext_vector_type(8)));
typedef float f32x4  __attribute__((ext_vector_type(4)));

__device__ __forceinline__ float ssp_f(float t){
  // softplus(t) - ln2, numerically stable
  return fmaxf(t, 0.0f) + __logf(1.0f + __expf(-fabsf(t))) - LN2F;
}
__device__ __forceinline__ unsigned short f2bf_u(float f){
  __hip_bfloat16 b = __float2bfloat16(f);
  return *reinterpret_cast<unsigned short*>(&b);
}
__device__ __forceinline__ float bf2f(unsigned short u){
  __hip_bfloat16 b = *reinterpret_cast<__hip_bfloat16*>(&u);
  return __bfloat162float(b);
}

__device__ __forceinline__ int load_idx(const void* ei, int is32, size_t pos){
  return is32 ? ((const int*)ei)[pos] : (int)(((const long long*)ei)[pos]);
}

struct WPtrs { const float* w[16]; };

// ---------------- fused setup (zero count + idx-width detect) + weight prep -
__global__ __launch_bounds__(256) void setup_prep_kernel(
    const unsigned* __restrict__ ei, int* __restrict__ flag,
    int* __restrict__ count, int N, int nzb,
    WPtrs p, int nw, unsigned short* __restrict__ wfrag,
    const float* __restrict__ WG, unsigned short* __restrict__ wgfrag){
  const int m = blockIdx.x;
  if (m < nzb){
    int i = m * 256 + threadIdx.x;
    if (i < N) count[i] = 0;
    if (m == 0){
      __shared__ int cnt;
      if (threadIdx.x == 0) cnt = 0;
      __syncthreads();
      int nz = 0;
      for (int k = threadIdx.x; k < 1024; k += 256)
        nz += (ei[2*k + 1] != 0u) ? 1 : 0;
      atomicAdd(&cnt, nz);
      __syncthreads();
      // int32 data: odd words are real indices (~all nonzero). int64: high words 0.
      if (threadIdx.x == 0) *flag = (cnt > 64) ? 1 : 0;
    }
  } else if (m < nzb + nw){
    const int w = m - nzb;
    const float* __restrict__ W = p.w[w];
    unsigned short* __restrict__ out = wfrag + (size_t)w * 16384;
    for (int q = threadIdx.x; q < 16384; q += 256){
      int i = q & 7, lane = (q >> 3) & 63, kt = (q >> 9) & 3, ct = q >> 11;
      int row = ct*16 + (lane & 15);
      int k   = kt*32 + (lane >> 4)*8 + i;
      out[q] = f2bf_u(W[row*128 + k]);
    }
  } else {
    const int b = m - nzb - nw;           // 0..3, each covers 2048 of 8192
    for (int qq = threadIdx.x; qq < 2048; qq += 256){
      int q = b*2048 + qq;
      int i = q & 7, lane = (q >> 3) & 63, kt = (q >> 9) & 1, nt = q >> 10; // nt 0..7
      int f = nt*16 + (lane & 15);
      int k = kt*32 + (lane >> 4)*8 + i;
      wgfrag[q] = f2bf_u(WG[(size_t)f*64 + k]);
    }
  }
}

// ---------------- CSR build ------------------------------------------------
__global__ void hist_kernel(const void* __restrict__ ei, const int* __restrict__ flag,
                            int* __restrict__ count, int E){
  const int is32 = *flag;
  for (long long e = (long long)blockIdx.x * 256 + threadIdx.x; e < E;
       e += (long long)gridDim.x * 256){
    int d = load_idx(ei, is32, (size_t)((long long)E + e));
    atomicAdd(&count[d], 1);
  }
}

__global__ __launch_bounds__(256) void scan1_kernel(const int* __restrict__ count,
                                                    int* __restrict__ bsum, int N){
  __shared__ int red[256];
  const int t = threadIdx.x;
  int i0 = blockIdx.x * 2048 + t * 8;
  int s = 0;
  #pragma unroll
  for (int r = 0; r < 8; ++r){ int i = i0 + r; s += (i < N) ? count[i] : 0; }
  red[t] = s;
  __syncthreads();
  for (int off = 128; off > 0; off >>= 1){
    if (t < off) red[t] += red[t + off];
    __syncthreads();
  }
  if (t == 0) bsum[blockIdx.x] = red[0];
}

// local scan; per-block serial prefix of bsum (nbk <= ~32) replaces scan2
__global__ __launch_bounds__(256) void scan3_kernel(const int* __restrict__ count,
                                                    const int* __restrict__ bsum,
                                                    int* __restrict__ offs,
                                                    int* __restrict__ cur, int N, int nbk){
  __shared__ int red[256];
  const int t = threadIdx.x;
  int base = 0;
  for (int b = 0; b < blockIdx.x; ++b) base += bsum[b];
  int i0 = blockIdx.x * 2048 + t * 8;
  int v[8];
  int s = 0;
  #pragma unroll
  for (int r = 0; r < 8; ++r){ int i = i0 + r; v[r] = (i < N) ? count[i] : 0; s += v[r]; }
  red[t] = s;
  __syncthreads();
  #pragma unroll
  for (int off = 1; off < 256; off <<= 1){
    int tv = (t >= off) ? red[t - off] : 0;
    __syncthreads();
    red[t] += tv;
    __syncthreads();
  }
  int run = red[t] - s + base;
  #pragma unroll
  for (int r = 0; r < 8; ++r){
    int i = i0 + r;
    if (i < N){ offs[i] = run; cur[i] = run; }
    run += v[r];
  }
  if (blockIdx.x == nbk - 1 && t == 255) offs[N] = run;
}

// se[slot] = (e, src), slots sorted by dst (CSR order)
__global__ void fill_kernel(const void* __restrict__ ei, const int* __restrict__ flag,
                            int* __restrict__ cur, int2* __restrict__ se, int E){
  const int is32 = *flag;
  for (long long e = (long long)blockIdx.x * 256 + threadIdx.x; e < E;
       e += (long long)gridDim.x * 256){
    int s = load_idx(ei, is32, (size_t)e);
    int d = load_idx(ei, is32, (size_t)((long long)E + e));
    int slot = atomicAdd(&cur[d], 1);
    se[slot] = make_int2((int)e, s);
  }
}

// ---------------- MFMA GEMM core: 128-row A slab (swizzled), K=128 --------
// A_s: bf16 [128][128], element (row,col) at row*128 + (col ^ ((row&7)<<3)).
// Bf: 16384 bf16 fragment-linear. acc[ct][q] = C[rbase+(lane>>4)*4+q][ct*16+(lane&15)]
__device__ __forceinline__ void mfma_gemm128s(const unsigned short* __restrict__ A_s,
                                              const unsigned short* __restrict__ Bf,
                                              int rbase, int lane, f32x4 acc[8]){
  #pragma unroll
  for (int ct = 0; ct < 8; ++ct) acc[ct] = (f32x4){0.f, 0.f, 0.f, 0.f};
  const int r  = rbase + (lane & 15);
  const int kg = lane >> 4;
  const int sw = (r & 7) << 3;
  #pragma unroll
  for (int kt = 0; kt < 4; ++kt){
    bf16x8 a = *(const bf16x8*)&A_s[r*128 + ((kt*32 + kg*8) ^ sw)];
    #pragma unroll
    for (int ct = 0; ct < 8; ++ct){
      bf16x8 b = *(const bf16x8*)&Bf[(size_t)((ct*4 + kt)*64 + lane)*8];
      acc[ct] = __builtin_amdgcn_mfma_f32_16x16x32_bf16(a, b, acc[ct], 0, 0, 0);
    }
  }
}

__device__ __forceinline__ void stage_bf512(unsigned short* __restrict__ Bf,
                                            const unsigned short* __restrict__ src, int t){
  #pragma unroll
  for (int it = 0; it < 4; ++it){
    int off = (it*512 + t) * 8;
    *(uint4*)&Bf[off] = *(const uint4*)&src[off];
  }
}

// ---------------- kernel 1: h = bf16(ssp(xa W_diff^T+b)), msged = ssp(xa W_same^T+b)
__global__ __launch_bounds__(512) void node_dual_kernel(
    const float* __restrict__ x, const unsigned short* __restrict__ wfrag,
    const float* __restrict__ bsame, const float* __restrict__ bdiff,
    unsigned short* __restrict__ hbf, float* __restrict__ msged, int N){
  __shared__ __align__(16) unsigned short A_s[128*128];
  __shared__ __align__(16) unsigned short Bf[16384];
  const int t = threadIdx.x, wv = t >> 6, lane = t & 63;
  const int kg = lane >> 4, c = lane & 15;
  const int row0 = blockIdx.x * 128;
  for (int q = t; q < 2048; q += 512){
    int row = q >> 4, c0 = (q & 15) * 8;
    float4 va = make_float4(0.f,0.f,0.f,0.f), vb = va;
    if (row0 + row < N){
      va = *(const float4*)&x[(size_t)(row0 + row)*128 + c0];
      vb = *(const float4*)&x[(size_t)(row0 + row)*128 + c0 + 4];
    }
    uint4 w;
    w.x = f2bf_u(ssp_f(va.x)) | ((unsigned)f2bf_u(ssp_f(va.y)) << 16);
    w.y = f2bf_u(ssp_f(va.z)) | ((unsigned)f2bf_u(ssp_f(va.w)) << 16);
    w.z = f2bf_u(ssp_f(vb.x)) | ((unsigned)f2bf_u(ssp_f(vb.y)) << 16);
    w.w = f2bf_u(ssp_f(vb.z)) | ((unsigned)f2bf_u(ssp_f(vb.w)) << 16);
    *(uint4*)&A_s[row*128 + (c0 ^ ((row & 7) << 3))] = w;
  }
  stage_bf512(Bf, wfrag, t);            // W_same
  __syncthreads();
  f32x4 acc[8];
  mfma_gemm128s(A_s, Bf, wv*16, lane, acc);
  #pragma unroll
  for (int ct = 0; ct < 8; ++ct){
    int col = ct*16 + c;
    float bv = bsame[col];
    #pragma unroll
    for (int q = 0; q < 4; ++q){
      int gr = row0 + wv*16 + kg*4 + q;
      if (gr < N) msged[(size_t)gr*128 + col] = ssp_f(acc[ct][q] + bv);
    }
  }
  __syncthreads();
  stage_bf512(Bf, wfrag + 16384, t);    // W_diff
  __syncthreads();
  mfma_gemm128s(A_s, Bf, wv*16, lane, acc);
  #pragma unroll
  for (int ct = 0; ct < 8; ++ct){
    int col = ct*16 + c;
    float bv = bdiff[col];
    #pragma unroll
    for (int q = 0; q < 4; ++q){
      int gr = row0 + wv*16 + kg*4 + q;
      if (gr < N) hbf[(size_t)gr*128 + col] = f2bf_u(ssp_f(acc[ct][q] + bv));
    }
  }
}

// ---------------- edge phase (round-10 version, at its measured floor) ----
// One wave owns a dst-aligned slot range and ALL 128 features. Per 16-slot
// batch: ea rows read ONCE (B operand), h rows staged to LDS once (16B/lane),
// gate for f=0..127 via 16 MFMAs (WG fragments in 64 VGPRs), then a reduce
// that multiplies gate*h from LDS and flushes full 512B msged rows per dst.
__global__ __launch_bounds__(256) void edge_mfma_kernel(
    const float* __restrict__ ea, const unsigned short* __restrict__ wgfrag,
    const unsigned short* __restrict__ h, const int2* __restrict__ se,
    const int* __restrict__ offs, float* __restrict__ msged, int N, int E, int KW){
  __shared__ float gate_s[4][16][132];
  __shared__ unsigned short h_s[4][16][136];
  const int t = threadIdx.x, wv = t >> 6, lane = t & 63;
  const int kg = lane >> 4, c = lane & 15;
  const int widx = blockIdx.x * 4 + wv;
  if (widx >= KW) return;
  long long tt0 = (long long)widx * E / KW;
  long long tt1 = (long long)(widx + 1) * E / KW;
  int lo = 0, hi = N;
  while (lo < hi){ int mid = (lo + hi) >> 1; if ((long long)offs[mid] < tt0) lo = mid + 1; else hi = mid; }
  const int d_lo = lo;
  hi = N;
  while (lo < hi){ int mid = (lo + hi) >> 1; if ((long long)offs[mid] < tt1) lo = mid + 1; else hi = mid; }
  const int d_hi = lo;
  if (d_lo >= d_hi) return;
  const int s_beg = offs[d_lo], s_end = offs[d_hi];
  if (s_beg >= s_end) return;

  // WG fragments for all 8 column-tiles (A operand), 64 VGPRs, loaded once
  bf16x8 aw[8][2];
  #pragma unroll
  for (int nt = 0; nt < 8; ++nt)
    #pragma unroll
    for (int kt = 0; kt < 2; ++kt)
      aw[nt][kt] = *(const bf16x8*)&wgfrag[(size_t)(((nt*2+kt)*64)+lane)*8];

  // boundary tracking with prefetched next-next offset
  int d_cur = d_lo;
  int no0 = offs[d_cur + 1];
  while (no0 == s_beg && d_cur + 1 < d_hi){ ++d_cur; no0 = offs[d_cur + 1]; }
  int no1 = (d_cur + 2 <= d_hi) ? offs[d_cur + 2] : 0x7FFFFFFF;

  float sum0 = 0.f, sum1 = 0.f;
  int p = s_beg;
  int nb = min(16, s_end - p);
  int2 s2 = se[p + min(c, nb - 1)];
  while (p < s_end){
    const int pn = p + 16;
    int2 s2n = s2;
    if (pn < s_end){
      int nbn = min(16, s_end - pn);
      s2n = se[pn + min(c, nbn - 1)];
    }
    // B fragments: lane's slot-c ea row, k slice kg*8..kg*8+7 (+kt*32) — read ONCE
    const float* __restrict__ ra = &ea[(size_t)s2.x * 64 + kg*8];
    float4 e00 = *(const float4*)&ra[0];
    float4 e01 = *(const float4*)&ra[4];
    float4 e10 = *(const float4*)&ra[32];
    float4 e11 = *(const float4*)&ra[36];

    // h staging: 16 rows x 256B -> LDS, 16B per lane per instr (4 instr)
    uint4 hreg[4];
    #pragma unroll
    for (int it = 0; it < 4; ++it){
      int j = it*64 + lane;
      int row = j >> 4, seg = j & 15;
      int sr = __shfl(s2.y, row, 16);
      hreg[it] = *(const uint4*)&h[(size_t)sr*128 + seg*8];
    }
    #pragma unroll
    for (int it = 0; it < 4; ++it){
      int j = it*64 + lane;
      int row = j >> 4, seg = j & 15;
      *(uint4*)&h_s[wv][row][seg*8] = hreg[it];
    }

    bf16x8 be0, be1;
    unsigned short* b0p = (unsigned short*)&be0;
    unsigned short* b1p = (unsigned short*)&be1;
    b0p[0]=f2bf_u(e00.x); b0p[1]=f2bf_u(e00.y); b0p[2]=f2bf_u(e00.z); b0p[3]=f2bf_u(e00.w);
    b0p[4]=f2bf_u(e01.x); b0p[5]=f2bf_u(e01.y); b0p[6]=f2bf_u(e01.z); b0p[7]=f2bf_u(e01.w);
    b1p[0]=f2bf_u(e10.x); b1p[1]=f2bf_u(e10.y); b1p[2]=f2bf_u(e10.z); b1p[3]=f2bf_u(e10.w);
    b1p[4]=f2bf_u(e11.x); b1p[5]=f2bf_u(e11.y); b1p[6]=f2bf_u(e11.z); b1p[7]=f2bf_u(e11.w);

    // gate for all 128 f: 16 MFMAs; write each f32x4 straight to LDS
    #pragma unroll
    for (int nt = 0; nt < 8; ++nt){
      f32x4 acc = (f32x4){0.f,0.f,0.f,0.f};
      acc = __builtin_amdgcn_mfma_f32_16x16x32_bf16(aw[nt][0], be0, acc, 0, 0, 0);
      acc = __builtin_amdgcn_mfma_f32_16x16x32_bf16(aw[nt][1], be1, acc, 0, 0, 0);
      *(f32x4*)&gate_s[wv][c][nt*16 + kg*4] = acc;
    }

    asm volatile("s_waitcnt lgkmcnt(0)" ::: "memory");  // h_s + gate_s visible

    const int nbc = min(16, s_end - p);
    #pragma unroll
    for (int i = 0; i < 16; ++i){
      if (i < nbc){
        float g0 = gate_s[wv][i][lane];
        float g1 = gate_s[wv][i][lane + 64];
        float h0 = bf2f(h_s[wv][i][lane]);
        float h1 = bf2f(h_s[wv][i][lane + 64]);
        sum0 = __builtin_fmaf(g0, h0, sum0);
        sum1 = __builtin_fmaf(g1, h1, sum1);
        if (p + i + 1 == no0){
          float* mp = &msged[(size_t)d_cur*128 + lane];
          mp[0]  += sum0;                 // owner-exclusive, full 512B row
          mp[64] += sum1;
          sum0 = 0.f; sum1 = 0.f;
          do {
            ++d_cur;
            no0 = no1;
            no1 = (d_cur + 2 <= d_hi) ? offs[d_cur + 2] : 0x7FFFFFFF;
          } while (no0 == p + i + 1);     // skip empty dst runs (rare)
        }
      }
    }
    p = pn; s2 = s2n;
  }
}

// ---------------- kernel 3: fused residual chain, 256-row blocks ----------
// 2 slabs per wave; Bf double-buffered (next weight loaded to regs before the
// gemm, landed after). A_s is wave-private (each wave reads only rows it
// writes) -> no barriers for A_s; one barrier per gemm for Bf.
__global__ __launch_bounds__(512) void tail_kernel(
    const float* __restrict__ msged, const float* __restrict__ x, const float* __restrict__ u,
    const unsigned short* __restrict__ wfrag,
    const float* __restrict__ rb1, const float* __restrict__ rb2,
    const float* __restrict__ blast, float* __restrict__ out0, int N, int NRES){
  __shared__ __align__(16) unsigned short A_s[256*128];   // 64 KB, 2 slabs
  __shared__ __align__(16) unsigned short Bf[2][16384];   // 64 KB
  const int t = threadIdx.x, wv = t >> 6, lane = t & 63;
  const int kg = lane >> 4, c = lane & 15;
  const int row0 = blockIdx.x * 256;

  float treg[2][8][4];
  #pragma unroll
  for (int sl = 0; sl < 2; ++sl)
    #pragma unroll
    for (int ct = 0; ct < 8; ++ct)
      #pragma unroll
      for (int q = 0; q < 4; ++q){
        int gr = row0 + sl*128 + wv*16 + kg*4 + q;
        float v = (gr < N) ? msged[(size_t)gr*128 + ct*16 + c] : 0.f;
        treg[sl][ct][q] = v;
        int row = sl*128 + wv*16 + kg*4 + q, col = ct*16 + c;
        A_s[row*128 + (col ^ ((row & 7) << 3))] = f2bf_u(ssp_f(v));
      }

  stage_bf512(Bf[0], wfrag + (size_t)2*16384, t);   // weight 0 = W1[0]
  __syncthreads();

  const int NG = 2*NRES + 1;                        // gemm count (weights 2..2+NG-1)
  int cur = 0;
  for (int g = 0; g < NG; ++g){
    const bool more = (g + 1 < NG);
    uint4 wr[4];
    if (more){                                      // issue next weight loads early
      const unsigned short* __restrict__ src = wfrag + (size_t)(3 + g)*16384;
      #pragma unroll
      for (int it = 0; it < 4; ++it) wr[it] = *(const uint4*)&src[(it*512 + t)*8];
    }
    const int l = g >> 1;
    #pragma unroll
    for (int sl = 0; sl < 2; ++sl){
      f32x4 acc[8];
      mfma_gemm128s(A_s + sl*16384, Bf[cur], wv*16, lane, acc);
      if (g == NG - 1){                             // W_last: write output
        #pragma unroll
        for (int ct = 0; ct < 8; ++ct){
          int col = ct*16 + c;
          float bv = blast[col], uv = u[col];
          #pragma unroll
          for (int q = 0; q < 4; ++q){
            int gr = row0 + sl*128 + wv*16 + kg*4 + q;
            if (gr < N){
              size_t idx = (size_t)gr*128 + col;
              out0[idx] = acc[ct][q] + bv + x[idx]*uv;
            }
          }
        }
      } else if ((g & 1) == 0){                     // after W1[l]: A_s = ssp(acc+b1)
        #pragma unroll
        for (int ct = 0; ct < 8; ++ct){
          float bv = rb1[l*128 + ct*16 + c];
          #pragma unroll
          for (int q = 0; q < 4; ++q){
            int row = sl*128 + wv*16 + kg*4 + q, col = ct*16 + c;
            A_s[row*128 + (col ^ ((row & 7) << 3))] = f2bf_u(ssp_f(acc[ct][q] + bv));
          }
        }
      } else {                                      // after W2[l]: treg += ; A_s = ssp(treg)
        #pragma unroll
        for (int ct = 0; ct < 8; ++ct){
          float bv = rb2[l*128 + ct*16 + c];
          #pragma unroll
          for (int q = 0; q < 4; ++q){
            treg[sl][ct][q] += acc[ct][q] + bv;
            int row = sl*128 + wv*16 + kg*4 + q, col = ct*16 + c;
            A_s[row*128 + (col ^ ((row & 7) << 3))] = f2bf_u(ssp_f(treg[sl][ct][q]));
          }
        }
      }
    }
    if (more){                                      // land next weight into other buffer
      #pragma unroll
      for (int it = 0; it < 4; ++it) *(uint4*)&Bf[cur ^ 1][(it*512 + t)*8] = wr[it];
    }
    __syncthreads();                                // Bf[cur] reads + Bf[cur^1] writes done
    cur ^= 1;
  }
}

extern "C" void kernel_launch(void* const* d_in, const int* in_sizes, int n_in,
                              void* d_out, int out_size, void* d_ws, size_t ws_size,
                              hipStream_t stream){
  const float* x     = (const float*)d_in[0];
  const void*  ei    = d_in[1];
  const float* ea    = (const float*)d_in[2];
  const float* Wsame = (const float*)d_in[3];
  const float* bsame = (const float*)d_in[4];
  const float* Wdiff = (const float*)d_in[5];
  const float* bdiff = (const float*)d_in[6];
  const float* WG    = (const float*)d_in[7];
  const float* rW1   = (const float*)d_in[8];
  const float* rb1   = (const float*)d_in[9];
  const float* rW2   = (const float*)d_in[10];
  const float* rb2   = (const float*)d_in[11];
  const float* Wlast = (const float*)d_in[12];
  const float* blast = (const float*)d_in[13];
  const float* u     = (const float*)d_in[14];

  const int N    = in_sizes[0] / 128;
  const int E    = in_sizes[1] / 2;
  int NRES = in_sizes[8] / (128*128);
  if (NRES > 6) NRES = 6;               // WPtrs capacity guard

  float* out0  = (float*)d_out;
  float* msged = (float*)d_out + (size_t)N * 128;   // second output, built in place

  auto align256 = [](size_t v){ return (v + 255) & ~(size_t)255; };
  const size_t o_h      = 256;
  const size_t o_count  = align256(o_h      + (size_t)N * 128 * 2);   // h is bf16
  const size_t o_off    = align256(o_count  + (size_t)N * 4);
  const size_t o_cur    = align256(o_off    + (size_t)(N + 1) * 4);
  const size_t o_se     = align256(o_cur    + (size_t)N * 4);
  const size_t o_bsum   = align256(o_se     + (size_t)E * 8);
  const size_t o_wfrag  = align256(o_bsum   + (size_t)4096 * 4);
  const size_t o_wgfrag = align256(o_wfrag  + (size_t)16 * 16384 * 2);

  int*   flag = (int*)d_ws;
  unsigned short* hbf = (unsigned short*)((char*)d_ws + o_h);
  int* count  = (int*)((char*)d_ws + o_count);
  int* offs   = (int*)((char*)d_ws + o_off);
  int* cur    = (int*)((char*)d_ws + o_cur);
  int2* se    = (int2*)((char*)d_ws + o_se);
  int* bsum   = (int*)((char*)d_ws + o_bsum);
  unsigned short* wfrag  = (unsigned short*)((char*)d_ws + o_wfrag);
  unsigned short* wgfrag = (unsigned short*)((char*)d_ws + o_wgfrag);
  (void)ws_size;

  const int nw = 3 + 2*NRES;            // same, diff, (W1,W2)*NRES, last
  WPtrs wp;
  wp.w[0] = Wsame;
  wp.w[1] = Wdiff;
  for (int l = 0; l < NRES; ++l){
    wp.w[2 + 2*l] = rW1 + (size_t)l*16384;
    wp.w[3 + 2*l] = rW2 + (size_t)l*16384;
  }
  wp.w[2 + 2*NRES] = Wlast;
  for (int i = nw; i < 16; ++i) wp.w[i] = Wlast;

  const int nb_node  = (N + 127) / 128;
  const int nb_node2 = (N + 255) / 256;
  const int nzb      = (N + 255) / 256;
  const int nbk      = (N + 2047) / 2048;
  const int nb_edge  = 2048;
  const int KW = nb_edge * 4;           // one wave covers all 128 features

  setup_prep_kernel<<<nzb + nw + 4, 256, 0, stream>>>((const unsigned*)ei, flag, count, N,
                                                      nzb, wp, nw, wfrag, WG, wgfrag);
  node_dual_kernel<<<nb_node, 512, 0, stream>>>(x, wfrag, bsame, bdiff, hbf, msged, N);

  hist_kernel<<<1024, 256, 0, stream>>>(ei, flag, count, E);
  scan1_kernel<<<nbk, 256, 0, stream>>>(count, bsum, N);
  scan3_kernel<<<nbk, 256, 0, stream>>>(count, bsum, offs, cur, N, nbk);
  fill_kernel<<<1024, 256, 0, stream>>>(ei, flag, cur, se, E);

  edge_mfma_kernel<<<nb_edge, 256, 0, stream>>>(ea, wgfrag, hbf, se, offs, msged, N, E, KW);

  tail_kernel<<<nb_node2, 512, 0, stream>>>(msged, x, u, wfrag, rb1, rb2, blast,
                                            out0, N, NRES);
}

// Round 13
// 356.261 us; speedup vs baseline: 1.3571x; 1.3571x over previous
//
#include <hip/hip_runtime.h>
#include <hip/hip_bf16.h>

#define LN2F 0.69314718055994530942f

typedef short bf16x8 __attribute__((ext_vector_type(8)));
typedef float f32x4  __attribute__((ext_vector_type(4)));

__device__ __forceinline__ float ssp_f(float t){
  // softplus(t) - ln2, numerically stable
  return fmaxf(t, 0.0f) + __logf(1.0f + __expf(-fabsf(t))) - LN2F;
}
__device__ __forceinline__ unsigned short f2bf_u(float f){
  __hip_bfloat16 b = __float2bfloat16(f);
  return *reinterpret_cast<unsigned short*>(&b);
}
__device__ __forceinline__ float bf2f(unsigned short u){
  __hip_bfloat16 b = *reinterpret_cast<__hip_bfloat16*>(&u);
  return __bfloat162float(b);
}

__device__ __forceinline__ int load_idx(const void* ei, int is32, size_t pos){
  return is32 ? ((const int*)ei)[pos] : (int)(((const long long*)ei)[pos]);
}

struct WPtrs { const float* w[16]; };

// ---------------- fused setup (zero count + idx-width detect) + weight prep -
__global__ __launch_bounds__(256) void setup_prep_kernel(
    const unsigned* __restrict__ ei, int* __restrict__ flag,
    int* __restrict__ count, int N, int nzb,
    WPtrs p, int nw, unsigned short* __restrict__ wfrag,
    const float* __restrict__ WG, unsigned short* __restrict__ wgfrag){
  const int m = blockIdx.x;
  if (m < nzb){
    int i = m * 256 + threadIdx.x;
    if (i < N) count[i] = 0;
    if (m == 0){
      __shared__ int cnt;
      if (threadIdx.x == 0) cnt = 0;
      __syncthreads();
      int nz = 0;
      for (int k = threadIdx.x; k < 1024; k += 256)
        nz += (ei[2*k + 1] != 0u) ? 1 : 0;
      atomicAdd(&cnt, nz);
      __syncthreads();
      // int32 data: odd words are real indices (~all nonzero). int64: high words 0.
      if (threadIdx.x == 0) *flag = (cnt > 64) ? 1 : 0;
    }
  } else if (m < nzb + nw){
    const int w = m - nzb;
    const float* __restrict__ W = p.w[w];
    unsigned short* __restrict__ out = wfrag + (size_t)w * 16384;
    for (int q = threadIdx.x; q < 16384; q += 256){
      int i = q & 7, lane = (q >> 3) & 63, kt = (q >> 9) & 3, ct = q >> 11;
      int row = ct*16 + (lane & 15);
      int k   = kt*32 + (lane >> 4)*8 + i;
      out[q] = f2bf_u(W[row*128 + k]);
    }
  } else {
    const int b = m - nzb - nw;           // 0..3, each covers 2048 of 8192
    for (int qq = threadIdx.x; qq < 2048; qq += 256){
      int q = b*2048 + qq;
      int i = q & 7, lane = (q >> 3) & 63, kt = (q >> 9) & 1, nt = q >> 10; // nt 0..7
      int f = nt*16 + (lane & 15);
      int k = kt*32 + (lane >> 4)*8 + i;
      wgfrag[q] = f2bf_u(WG[(size_t)f*64 + k]);
    }
  }
}

// ---------------- CSR build ------------------------------------------------
__global__ void hist_kernel(const void* __restrict__ ei, const int* __restrict__ flag,
                            int* __restrict__ count, int E){
  const int is32 = *flag;
  for (long long e = (long long)blockIdx.x * 256 + threadIdx.x; e < E;
       e += (long long)gridDim.x * 256){
    int d = load_idx(ei, is32, (size_t)((long long)E + e));
    atomicAdd(&count[d], 1);
  }
}

__global__ __launch_bounds__(256) void scan1_kernel(const int* __restrict__ count,
                                                    int* __restrict__ bsum, int N){
  __shared__ int red[256];
  const int t = threadIdx.x;
  int i0 = blockIdx.x * 2048 + t * 8;
  int s = 0;
  #pragma unroll
  for (int r = 0; r < 8; ++r){ int i = i0 + r; s += (i < N) ? count[i] : 0; }
  red[t] = s;
  __syncthreads();
  for (int off = 128; off > 0; off >>= 1){
    if (t < off) red[t] += red[t + off];
    __syncthreads();
  }
  if (t == 0) bsum[blockIdx.x] = red[0];
}

// local scan; per-block serial prefix of bsum (nbk <= ~32) replaces scan2
__global__ __launch_bounds__(256) void scan3_kernel(const int* __restrict__ count,
                                                    const int* __restrict__ bsum,
                                                    int* __restrict__ offs,
                                                    int* __restrict__ cur, int N, int nbk){
  __shared__ int red[256];
  const int t = threadIdx.x;
  int base = 0;
  for (int b = 0; b < blockIdx.x; ++b) base += bsum[b];
  int i0 = blockIdx.x * 2048 + t * 8;
  int v[8];
  int s = 0;
  #pragma unroll
  for (int r = 0; r < 8; ++r){ int i = i0 + r; v[r] = (i < N) ? count[i] : 0; s += v[r]; }
  red[t] = s;
  __syncthreads();
  #pragma unroll
  for (int off = 1; off < 256; off <<= 1){
    int tv = (t >= off) ? red[t - off] : 0;
    __syncthreads();
    red[t] += tv;
    __syncthreads();
  }
  int run = red[t] - s + base;
  #pragma unroll
  for (int r = 0; r < 8; ++r){
    int i = i0 + r;
    if (i < N){ offs[i] = run; cur[i] = run; }
    run += v[r];
  }
  if (blockIdx.x == nbk - 1 && t == 255) offs[N] = run;
}

// se[slot] = (e, src), slots sorted by dst (CSR order)
__global__ void fill_kernel(const void* __restrict__ ei, const int* __restrict__ flag,
                            int* __restrict__ cur, int2* __restrict__ se, int E){
  const int is32 = *flag;
  for (long long e = (long long)blockIdx.x * 256 + threadIdx.x; e < E;
       e += (long long)gridDim.x * 256){
    int s = load_idx(ei, is32, (size_t)e);
    int d = load_idx(ei, is32, (size_t)((long long)E + e));
    int slot = atomicAdd(&cur[d], 1);
    se[slot] = make_int2((int)e, s);
  }
}

// ---------------- MFMA GEMM core: 128-row A tile (swizzled), K=128 --------
// A_s: bf16 [128][128], element (row,col) at row*128 + (col ^ ((row&7)<<3)).
// Bf: 16384 bf16 fragment-linear. acc[ct][q] = C[rbase+(lane>>4)*4+q][ct*16+(lane&15)]
__device__ __forceinline__ void mfma_gemm128s(const unsigned short* __restrict__ A_s,
                                              const unsigned short* __restrict__ Bf,
                                              int rbase, int lane, f32x4 acc[8]){
  #pragma unroll
  for (int ct = 0; ct < 8; ++ct) acc[ct] = (f32x4){0.f, 0.f, 0.f, 0.f};
  const int r  = rbase + (lane & 15);
  const int kg = lane >> 4;
  const int sw = (r & 7) << 3;
  #pragma unroll
  for (int kt = 0; kt < 4; ++kt){
    bf16x8 a = *(const bf16x8*)&A_s[r*128 + ((kt*32 + kg*8) ^ sw)];
    #pragma unroll
    for (int ct = 0; ct < 8; ++ct){
      bf16x8 b = *(const bf16x8*)&Bf[(size_t)((ct*4 + kt)*64 + lane)*8];
      acc[ct] = __builtin_amdgcn_mfma_f32_16x16x32_bf16(a, b, acc[ct], 0, 0, 0);
    }
  }
}

__device__ __forceinline__ void stage_bf512(unsigned short* __restrict__ Bf,
                                            const unsigned short* __restrict__ src, int t){
  #pragma unroll
  for (int it = 0; it < 4; ++it){
    int off = (it*512 + t) * 8;
    *(uint4*)&Bf[off] = *(const uint4*)&src[off];
  }
}

// ---------------- kernel 1: h = bf16(ssp(xa W_diff^T+b)), msged = ssp(xa W_same^T+b)
__global__ __launch_bounds__(512) void node_dual_kernel(
    const float* __restrict__ x, const unsigned short* __restrict__ wfrag,
    const float* __restrict__ bsame, const float* __restrict__ bdiff,
    unsigned short* __restrict__ hbf, float* __restrict__ msged, int N){
  __shared__ __align__(16) unsigned short A_s[128*128];
  __shared__ __align__(16) unsigned short Bf[16384];
  const int t = threadIdx.x, wv = t >> 6, lane = t & 63;
  const int kg = lane >> 4, c = lane & 15;
  const int row0 = blockIdx.x * 128;
  for (int q = t; q < 2048; q += 512){
    int row = q >> 4, c0 = (q & 15) * 8;
    float4 va = make_float4(0.f,0.f,0.f,0.f), vb = va;
    if (row0 + row < N){
      va = *(const float4*)&x[(size_t)(row0 + row)*128 + c0];
      vb = *(const float4*)&x[(size_t)(row0 + row)*128 + c0 + 4];
    }
    uint4 w;
    w.x = f2bf_u(ssp_f(va.x)) | ((unsigned)f2bf_u(ssp_f(va.y)) << 16);
    w.y = f2bf_u(ssp_f(va.z)) | ((unsigned)f2bf_u(ssp_f(va.w)) << 16);
    w.z = f2bf_u(ssp_f(vb.x)) | ((unsigned)f2bf_u(ssp_f(vb.y)) << 16);
    w.w = f2bf_u(ssp_f(vb.z)) | ((unsigned)f2bf_u(ssp_f(vb.w)) << 16);
    *(uint4*)&A_s[row*128 + (c0 ^ ((row & 7) << 3))] = w;
  }
  stage_bf512(Bf, wfrag, t);            // W_same
  __syncthreads();
  f32x4 acc[8];
  mfma_gemm128s(A_s, Bf, wv*16, lane, acc);
  #pragma unroll
  for (int ct = 0; ct < 8; ++ct){
    int col = ct*16 + c;
    float bv = bsame[col];
    #pragma unroll
    for (int q = 0; q < 4; ++q){
      int gr = row0 + wv*16 + kg*4 + q;
      if (gr < N) msged[(size_t)gr*128 + col] = ssp_f(acc[ct][q] + bv);
    }
  }
  __syncthreads();
  stage_bf512(Bf, wfrag + 16384, t);    // W_diff
  __syncthreads();
  mfma_gemm128s(A_s, Bf, wv*16, lane, acc);
  #pragma unroll
  for (int ct = 0; ct < 8; ++ct){
    int col = ct*16 + c;
    float bv = bdiff[col];
    #pragma unroll
    for (int q = 0; q < 4; ++q){
      int gr = row0 + wv*16 + kg*4 + q;
      if (gr < N) hbf[(size_t)gr*128 + col] = f2bf_u(ssp_f(acc[ct][q] + bv));
    }
  }
}

// ---------------- edge phase (measured floor ~153 us) ---------------------
// One wave owns a dst-aligned slot range and ALL 128 features. Per 16-slot
// batch: ea rows read ONCE (B operand), h rows staged to LDS once (16B/lane),
// gate for f=0..127 via 16 MFMAs (WG fragments in 64 VGPRs), then a reduce
// that multiplies gate*h from LDS and flushes full 512B msged rows per dst.
__global__ __launch_bounds__(256) void edge_mfma_kernel(
    const float* __restrict__ ea, const unsigned short* __restrict__ wgfrag,
    const unsigned short* __restrict__ h, const int2* __restrict__ se,
    const int* __restrict__ offs, float* __restrict__ msged, int N, int E, int KW){
  __shared__ float gate_s[4][16][132];
  __shared__ unsigned short h_s[4][16][136];
  const int t = threadIdx.x, wv = t >> 6, lane = t & 63;
  const int kg = lane >> 4, c = lane & 15;
  const int widx = blockIdx.x * 4 + wv;
  if (widx >= KW) return;
  long long tt0 = (long long)widx * E / KW;
  long long tt1 = (long long)(widx + 1) * E / KW;
  int lo = 0, hi = N;
  while (lo < hi){ int mid = (lo + hi) >> 1; if ((long long)offs[mid] < tt0) lo = mid + 1; else hi = mid; }
  const int d_lo = lo;
  hi = N;
  while (lo < hi){ int mid = (lo + hi) >> 1; if ((long long)offs[mid] < tt1) lo = mid + 1; else hi = mid; }
  const int d_hi = lo;
  if (d_lo >= d_hi) return;
  const int s_beg = offs[d_lo], s_end = offs[d_hi];
  if (s_beg >= s_end) return;

  // WG fragments for all 8 column-tiles (A operand), 64 VGPRs, loaded once
  bf16x8 aw[8][2];
  #pragma unroll
  for (int nt = 0; nt < 8; ++nt)
    #pragma unroll
    for (int kt = 0; kt < 2; ++kt)
      aw[nt][kt] = *(const bf16x8*)&wgfrag[(size_t)(((nt*2+kt)*64)+lane)*8];

  // boundary tracking with prefetched next-next offset
  int d_cur = d_lo;
  int no0 = offs[d_cur + 1];
  while (no0 == s_beg && d_cur + 1 < d_hi){ ++d_cur; no0 = offs[d_cur + 1]; }
  int no1 = (d_cur + 2 <= d_hi) ? offs[d_cur + 2] : 0x7FFFFFFF;

  float sum0 = 0.f, sum1 = 0.f;
  int p = s_beg;
  int nb = min(16, s_end - p);
  int2 s2 = se[p + min(c, nb - 1)];
  while (p < s_end){
    const int pn = p + 16;
    int2 s2n = s2;
    if (pn < s_end){
      int nbn = min(16, s_end - pn);
      s2n = se[pn + min(c, nbn - 1)];
    }
    // B fragments: lane's slot-c ea row, k slice kg*8..kg*8+7 (+kt*32) — read ONCE
    const float* __restrict__ ra = &ea[(size_t)s2.x * 64 + kg*8];
    float4 e00 = *(const float4*)&ra[0];
    float4 e01 = *(const float4*)&ra[4];
    float4 e10 = *(const float4*)&ra[32];
    float4 e11 = *(const float4*)&ra[36];

    // h staging: 16 rows x 256B -> LDS, 16B per lane per instr (4 instr)
    uint4 hreg[4];
    #pragma unroll
    for (int it = 0; it < 4; ++it){
      int j = it*64 + lane;
      int row = j >> 4, seg = j & 15;
      int sr = __shfl(s2.y, row, 16);
      hreg[it] = *(const uint4*)&h[(size_t)sr*128 + seg*8];
    }
    #pragma unroll
    for (int it = 0; it < 4; ++it){
      int j = it*64 + lane;
      int row = j >> 4, seg = j & 15;
      *(uint4*)&h_s[wv][row][seg*8] = hreg[it];
    }

    bf16x8 be0, be1;
    unsigned short* b0p = (unsigned short*)&be0;
    unsigned short* b1p = (unsigned short*)&be1;
    b0p[0]=f2bf_u(e00.x); b0p[1]=f2bf_u(e00.y); b0p[2]=f2bf_u(e00.z); b0p[3]=f2bf_u(e00.w);
    b0p[4]=f2bf_u(e01.x); b0p[5]=f2bf_u(e01.y); b0p[6]=f2bf_u(e01.z); b0p[7]=f2bf_u(e01.w);
    b1p[0]=f2bf_u(e10.x); b1p[1]=f2bf_u(e10.y); b1p[2]=f2bf_u(e10.z); b1p[3]=f2bf_u(e10.w);
    b1p[4]=f2bf_u(e11.x); b1p[5]=f2bf_u(e11.y); b1p[6]=f2bf_u(e11.z); b1p[7]=f2bf_u(e11.w);

    // gate for all 128 f: 16 MFMAs; write each f32x4 straight to LDS
    #pragma unroll
    for (int nt = 0; nt < 8; ++nt){
      f32x4 acc = (f32x4){0.f,0.f,0.f,0.f};
      acc = __builtin_amdgcn_mfma_f32_16x16x32_bf16(aw[nt][0], be0, acc, 0, 0, 0);
      acc = __builtin_amdgcn_mfma_f32_16x16x32_bf16(aw[nt][1], be1, acc, 0, 0, 0);
      *(f32x4*)&gate_s[wv][c][nt*16 + kg*4] = acc;
    }

    asm volatile("s_waitcnt lgkmcnt(0)" ::: "memory");  // h_s + gate_s visible

    const int nbc = min(16, s_end - p);
    #pragma unroll
    for (int i = 0; i < 16; ++i){
      if (i < nbc){
        float g0 = gate_s[wv][i][lane];
        float g1 = gate_s[wv][i][lane + 64];
        float h0 = bf2f(h_s[wv][i][lane]);
        float h1 = bf2f(h_s[wv][i][lane + 64]);
        sum0 = __builtin_fmaf(g0, h0, sum0);
        sum1 = __builtin_fmaf(g1, h1, sum1);
        if (p + i + 1 == no0){
          float* mp = &msged[(size_t)d_cur*128 + lane];
          mp[0]  += sum0;                 // owner-exclusive, full 512B row
          mp[64] += sum1;
          sum0 = 0.f; sum1 = 0.f;
          do {
            ++d_cur;
            no0 = no1;
            no1 = (d_cur + 2 <= d_hi) ? offs[d_cur + 2] : 0x7FFFFFFF;
          } while (no0 == p + i + 1);     // skip empty dst runs (rare)
        }
      }
    }
    p = pn; s2 = s2n;
  }
}

// ---------------- kernel 3: fused residual chain + final linear + skip ----
// 128-row blocks, 64 KB LDS -> 2 blocks/CU (the measured sweet spot).
__global__ __launch_bounds__(512) void tail_kernel(
    const float* __restrict__ msged, const float* __restrict__ x, const float* __restrict__ u,
    const unsigned short* __restrict__ wfrag,
    const float* __restrict__ rb1, const float* __restrict__ rb2,
    const float* __restrict__ blast, float* __restrict__ out0, int N, int NRES){
  __shared__ __align__(16) unsigned short A_s[128*128];
  __shared__ __align__(16) unsigned short Bf[16384];
  const int t = threadIdx.x, wv = t >> 6, lane = t & 63;
  const int kg = lane >> 4, c = lane & 15;
  const int row0 = blockIdx.x * 128;

  float treg[8][4];
  #pragma unroll
  for (int ct = 0; ct < 8; ++ct)
    #pragma unroll
    for (int q = 0; q < 4; ++q){
      int gr = row0 + wv*16 + kg*4 + q;
      treg[ct][q] = (gr < N) ? msged[(size_t)gr*128 + ct*16 + c] : 0.f;
    }

  f32x4 acc[8];
  for (int l = 0; l < NRES; ++l){
    __syncthreads();                    // previous A_s/Bf readers done
    #pragma unroll
    for (int ct = 0; ct < 8; ++ct)
      #pragma unroll
      for (int q = 0; q < 4; ++q){
        int row = wv*16 + kg*4 + q, col = ct*16 + c;
        A_s[row*128 + (col ^ ((row & 7) << 3))] = f2bf_u(ssp_f(treg[ct][q]));
      }
    stage_bf512(Bf, wfrag + (size_t)(2 + 2*l)*16384, t);
    __syncthreads();
    mfma_gemm128s(A_s, Bf, wv*16, lane, acc);
    __syncthreads();                    // A_s/Bf reads done before overwrite
    #pragma unroll
    for (int ct = 0; ct < 8; ++ct){
      float bv = rb1[l*128 + ct*16 + c];
      #pragma unroll
      for (int q = 0; q < 4; ++q){
        int row = wv*16 + kg*4 + q, col = ct*16 + c;
        A_s[row*128 + (col ^ ((row & 7) << 3))] = f2bf_u(ssp_f(acc[ct][q] + bv));
      }
    }
    stage_bf512(Bf, wfrag + (size_t)(3 + 2*l)*16384, t);
    __syncthreads();
    mfma_gemm128s(A_s, Bf, wv*16, lane, acc);
    #pragma unroll
    for (int ct = 0; ct < 8; ++ct){
      float bv = rb2[l*128 + ct*16 + c];
      #pragma unroll
      for (int q = 0; q < 4; ++q) treg[ct][q] += acc[ct][q] + bv;
    }
  }
  __syncthreads();
  #pragma unroll
  for (int ct = 0; ct < 8; ++ct)
    #pragma unroll
    for (int q = 0; q < 4; ++q){
      int row = wv*16 + kg*4 + q, col = ct*16 + c;
      A_s[row*128 + (col ^ ((row & 7) << 3))] = f2bf_u(ssp_f(treg[ct][q]));
    }
  stage_bf512(Bf, wfrag + (size_t)(2 + 2*NRES)*16384, t);
  __syncthreads();
  mfma_gemm128s(A_s, Bf, wv*16, lane, acc);
  #pragma unroll
  for (int ct = 0; ct < 8; ++ct){
    int col = ct*16 + c;
    float bv = blast[col];
    float uv = u[col];
    #pragma unroll
    for (int q = 0; q < 4; ++q){
      int gr = row0 + wv*16 + kg*4 + q;
      if (gr < N){
        size_t idx = (size_t)gr*128 + col;
        out0[idx] = acc[ct][q] + bv + x[idx]*uv;
      }
    }
  }
}

extern "C" void kernel_launch(void* const* d_in, const int* in_sizes, int n_in,
                              void* d_out, int out_size, void* d_ws, size_t ws_size,
                              hipStream_t stream){
  const float* x     = (const float*)d_in[0];
  const void*  ei    = d_in[1];
  const float* ea    = (const float*)d_in[2];
  const float* Wsame = (const float*)d_in[3];
  const float* bsame = (const float*)d_in[4];
  const float* Wdiff = (const float*)d_in[5];
  const float* bdiff = (const float*)d_in[6];
  const float* WG    = (const float*)d_in[7];
  const float* rW1   = (const float*)d_in[8];
  const float* rb1   = (const float*)d_in[9];
  const float* rW2   = (const float*)d_in[10];
  const float* rb2   = (const float*)d_in[11];
  const float* Wlast = (const float*)d_in[12];
  const float* blast = (const float*)d_in[13];
  const float* u     = (const float*)d_in[14];

  const int N    = in_sizes[0] / 128;
  const int E    = in_sizes[1] / 2;
  int NRES = in_sizes[8] / (128*128);
  if (NRES > 6) NRES = 6;               // WPtrs capacity guard

  float* out0  = (float*)d_out;
  float* msged = (float*)d_out + (size_t)N * 128;   // second output, built in place

  auto align256 = [](size_t v){ return (v + 255) & ~(size_t)255; };
  const size_t o_h      = 256;
  const size_t o_count  = align256(o_h      + (size_t)N * 128 * 2);   // h is bf16
  const size_t o_off    = align256(o_count  + (size_t)N * 4);
  const size_t o_cur    = align256(o_off    + (size_t)(N + 1) * 4);
  const size_t o_se     = align256(o_cur    + (size_t)N * 4);
  const size_t o_bsum   = align256(o_se     + (size_t)E * 8);
  const size_t o_wfrag  = align256(o_bsum   + (size_t)4096 * 4);
  const size_t o_wgfrag = align256(o_wfrag  + (size_t)16 * 16384 * 2);

  int*   flag = (int*)d_ws;
  unsigned short* hbf = (unsigned short*)((char*)d_ws + o_h);
  int* count  = (int*)((char*)d_ws + o_count);
  int* offs   = (int*)((char*)d_ws + o_off);
  int* cur    = (int*)((char*)d_ws + o_cur);
  int2* se    = (int2*)((char*)d_ws + o_se);
  int* bsum   = (int*)((char*)d_ws + o_bsum);
  unsigned short* wfrag  = (unsigned short*)((char*)d_ws + o_wfrag);
  unsigned short* wgfrag = (unsigned short*)((char*)d_ws + o_wgfrag);
  (void)ws_size;

  const int nw = 3 + 2*NRES;            // same, diff, (W1,W2)*NRES, last
  WPtrs wp;
  wp.w[0] = Wsame;
  wp.w[1] = Wdiff;
  for (int l = 0; l < NRES; ++l){
    wp.w[2 + 2*l] = rW1 + (size_t)l*16384;
    wp.w[3 + 2*l] = rW2 + (size_t)l*16384;
  }
  wp.w[2 + 2*NRES] = Wlast;
  for (int i = nw; i < 16; ++i) wp.w[i] = Wlast;

  const int nb_node = (N + 127) / 128;
  const int nzb     = (N + 255) / 256;
  const int nbk     = (N + 2047) / 2048;
  const int nb_edge = 2048;
  const int KW = nb_edge * 4;           // one wave covers all 128 features

  setup_prep_kernel<<<nzb + nw + 4, 256, 0, stream>>>((const unsigned*)ei, flag, count, N,
                                                      nzb, wp, nw, wfrag, WG, wgfrag);
  node_dual_kernel<<<nb_node, 512, 0, stream>>>(x, wfrag, bsame, bdiff, hbf, msged, N);

  hist_kernel<<<1024, 256, 0, stream>>>(ei, flag, count, E);
  scan1_kernel<<<nbk, 256, 0, stream>>>(count, bsum, N);
  scan3_kernel<<<nbk, 256, 0, stream>>>(count, bsum, offs, cur, N, nbk);
  fill_kernel<<<1024, 256, 0, stream>>>(ei, flag, cur, se, E);

  edge_mfma_kernel<<<nb_edge, 256, 0, stream>>>(ea, wgfrag, hbf, se, offs, msged, N, E, KW);

  tail_kernel<<<nb_node, 512, 0, stream>>>(msged, x, u, wfrag, rb1, rb2, blast,
                                           out0, N, NRES);
}